// Round 1
// baseline (73448.706 us; speedup 1.0000x reference)
//
#include <hip/hip_runtime.h>
#include <math.h>

static __device__ __forceinline__ float sigmoid_f(float x) {
    return 1.0f / (1.0f + expf(-x));
}

// ---------------------------------------------------------------------------
// conv k=4, s=2, p=1.  16x16 output tile per block (256 threads, 1 px/thread),
// G output channels per block.  Input patch staged in LDS; weights read as
// wave-uniform global loads (scalarized by the compiler).
// ---------------------------------------------------------------------------
template <int G>
__global__ __launch_bounds__(256) void conv_down_k4(
    const float* __restrict__ in, long in_b_stride,
    const float* __restrict__ w, const float* __restrict__ bias,
    float* __restrict__ out,
    int IC, int Hin, int Win, int OC, int Hout, int Wout, int tiles_x)
{
    constexpr int PS = 40;  // padded LDS row stride (floats)
    const int tile = blockIdx.x;
    const int ocg  = blockIdx.y;
    const int b    = blockIdx.z;
    const int oy0  = (tile / tiles_x) * 16;
    const int ox0  = (tile % tiles_x) * 16;
    const int tid  = threadIdx.x;
    const int txi  = tid & 15, tyi = tid >> 4;

    __shared__ float patch[34 * PS];

    float acc[G];
#pragma unroll
    for (int g = 0; g < G; ++g) acc[g] = 0.f;

    const int iy0 = 2 * oy0 - 1;
    const int ix0 = 2 * ox0 - 1;
    const float* inb = in + (long)b * in_b_stride;

    for (int ic = 0; ic < IC; ++ic) {
        const float* src = inb + (long)ic * Hin * Win;
        for (int p = tid; p < 34 * 34; p += 256) {
            int py = p / 34, px = p - py * 34;
            int iy = iy0 + py, ix = ix0 + px;
            float v = 0.f;
            if (iy >= 0 && iy < Hin && ix >= 0 && ix < Win) v = src[iy * Win + ix];
            patch[py * PS + px] = v;
        }
        __syncthreads();
        const float* wr = w + ((long)(ocg * G) * IC + ic) * 16;
#pragma unroll
        for (int ky = 0; ky < 4; ++ky) {
#pragma unroll
            for (int kx = 0; kx < 4; ++kx) {
                float v = patch[(2 * tyi + ky) * PS + 2 * txi + kx];
#pragma unroll
                for (int g = 0; g < G; ++g)
                    acc[g] += wr[(long)g * IC * 16 + ky * 4 + kx] * v;
            }
        }
        __syncthreads();
    }
    const int oy = oy0 + tyi, ox = ox0 + txi;
    const long ob = (long)b * OC * Hout * Wout;
#pragma unroll
    for (int g = 0; g < G; ++g) {
        int oc = ocg * G + g;
        out[ob + (long)oc * Hout * Wout + oy * Wout + ox] = acc[g] + bias[oc];
    }
}

// ---------------------------------------------------------------------------
// Fused ConvGRU 5x5 (pad 2) conv.  IC = 2C; channels [0,C) come from xt,
// channels [C,2C) come from src2 (h for the zr conv, r*h for the h~ conv).
// mode 0 (zr): out1 <- z = sigmoid(.), out2 <- rh = sigmoid(.)*h   (OC = 2C)
// mode 1 (h~): out1 <- (1-z)*h + z*tanh(.)                          (OC = C)
// Tile: (16*PY) x (16*PX) pixels, 256 threads, G=8 out-channels/block.
// LDS row stride 48 (offset 16 mod 32 -> free 2-way bank aliasing).
// Weights via wave-uniform (scalar) global loads.
// ---------------------------------------------------------------------------
template <int PY, int PX>
__global__ __launch_bounds__(256) void gru_conv5(
    const float* __restrict__ xt, const float* __restrict__ src2,
    const float* __restrict__ w, const float* __restrict__ bias,
    const float* __restrict__ h, const float* __restrict__ z,
    float* __restrict__ out1, float* __restrict__ out2,
    int C, int H, int W, int tiles_x, int mode)
{
    constexpr int G  = 8;
    constexpr int TH = 16 * PY, TW = 16 * PX;
    constexpr int PH = TH + 4, PW = TW + 4;
    constexpr int PS = 48;
    const int tile = blockIdx.x;
    const int ocg  = blockIdx.y;
    const int b    = blockIdx.z;
    const int oy0  = (tile / tiles_x) * TH;
    const int ox0  = (tile % tiles_x) * TW;
    const int tid  = threadIdx.x;
    const int txi  = tid & 15, tyi = tid >> 4;
    const int IC   = 2 * C;

    __shared__ float patch[PH * PS];

    float acc[G][PY * PX];
#pragma unroll
    for (int g = 0; g < G; ++g)
#pragma unroll
        for (int p = 0; p < PY * PX; ++p) acc[g][p] = 0.f;

    const long bC = (long)b * C * H * W;

    for (int ic = 0; ic < IC; ++ic) {
        const float* src = (ic < C) ? (xt + bC + (long)ic * H * W)
                                    : (src2 + bC + (long)(ic - C) * H * W);
        for (int p = tid; p < PH * PW; p += 256) {
            int py = p / PW, px = p - py * PW;
            int iy = oy0 - 2 + py, ix = ox0 - 2 + px;
            float v = 0.f;
            if (iy >= 0 && iy < H && ix >= 0 && ix < W) v = src[iy * W + ix];
            patch[py * PS + px] = v;
        }
        __syncthreads();
        const float* wr = w + ((long)(ocg * G) * IC + ic) * 25;
#pragma unroll
        for (int ky = 0; ky < 5; ++ky) {
#pragma unroll
            for (int kx = 0; kx < 5; ++kx) {
                float wv[G];
#pragma unroll
                for (int g = 0; g < G; ++g)
                    wv[g] = wr[(long)g * IC * 25 + ky * 5 + kx];
#pragma unroll
                for (int py = 0; py < PY; ++py)
#pragma unroll
                    for (int px = 0; px < PX; ++px) {
                        float v = patch[(tyi + 16 * py + ky) * PS + txi + 16 * px + kx];
#pragma unroll
                        for (int g = 0; g < G; ++g)
                            acc[g][py * PX + px] += wv[g] * v;
                    }
            }
        }
        __syncthreads();
    }

#pragma unroll
    for (int g = 0; g < G; ++g) {
        const int oc   = ocg * G + g;
        const float bv = bias[oc];
#pragma unroll
        for (int py = 0; py < PY; ++py)
#pragma unroll
            for (int px = 0; px < PX; ++px) {
                const int y = oy0 + tyi + 16 * py;
                const int x = ox0 + txi + 16 * px;
                float a = acc[g][py * PX + px] + bv;
                if (mode == 0) {
                    float s = sigmoid_f(a);
                    if (oc < C) {
                        out1[bC + (long)oc * H * W + y * W + x] = s;
                    } else {
                        long idx = bC + (long)(oc - C) * H * W + y * W + x;
                        out2[idx] = s * h[idx];
                    }
                } else {
                    long idx  = bC + (long)oc * H * W + y * W + x;
                    float zv  = z[idx];
                    float hv  = h[idx];
                    out1[idx] = (1.f - zv) * hv + zv * tanhf(a);
                }
            }
    }
}

// ---------------------------------------------------------------------------
extern "C" void kernel_launch(void* const* d_in, const int* in_sizes, int n_in,
                              void* d_out, int out_size, void* d_ws, size_t ws_size,
                              hipStream_t stream)
{
    (void)in_sizes; (void)n_in; (void)out_size; (void)ws_size;

    const float* input  = (const float*)d_in[0];
    const float* c1_w   = (const float*)d_in[1];
    const float* c1_b   = (const float*)d_in[2];
    const float* g1zr_w = (const float*)d_in[3];
    const float* g1zr_b = (const float*)d_in[4];
    const float* g1h_w  = (const float*)d_in[5];
    const float* g1h_b  = (const float*)d_in[6];
    const float* c2_w   = (const float*)d_in[7];
    const float* c2_b   = (const float*)d_in[8];
    const float* g2zr_w = (const float*)d_in[9];
    const float* g2zr_b = (const float*)d_in[10];
    const float* g2h_w  = (const float*)d_in[11];
    const float* g2h_b  = (const float*)d_in[12];
    const float* c3_w   = (const float*)d_in[13];
    const float* c3_b   = (const float*)d_in[14];
    const float* g3zr_w = (const float*)d_in[15];
    const float* g3zr_b = (const float*)d_in[16];
    const float* g3h_w  = (const float*)d_in[17];
    const float* g3h_b  = (const float*)d_in[18];

    float* out  = (float*)d_out;
    float* out1 = out;            // state1 [8,64,64,64]
    float* out2 = out + 2097152;  // state2 [8,128,32,32]
    float* out3 = out + 3145728;  // state3 [8,128,16,16]

    float* wsf = (float*)d_ws;
    size_t off = 0;
    auto take = [&](size_t n) { float* p = wsf + off; off += (n + 63) & ~(size_t)63; return p; };
    float* xt1 = take(2097152);   // [8,64,64,64]
    float* h1a = take(2097152);
    float* h1b = take(2097152);
    float* z1  = take(2097152);
    float* rh1 = take(2097152);
    float* xt2 = take(12582912);  // [12,8,128,32,32]
    float* h2a = take(1048576);
    float* h2b = take(1048576);
    float* z2  = take(1048576);
    float* rh2 = take(1048576);
    float* xt3 = take(3145728);   // [12,8,128,16,16]
    float* h3a = take(262144);
    float* h3b = take(262144);
    float* z3  = take(262144);
    float* rh3 = take(262144);

    hipMemsetAsync(h1a, 0, 2097152 * sizeof(float), stream);
    hipMemsetAsync(h2a, 0, 1048576 * sizeof(float), stream);
    hipMemsetAsync(h3a, 0, 262144 * sizeof(float), stream);

    // ---- stage 1 (k4s2 conv1 + GRU at 64x64, C=64), conv2 fused into loop ----
    {
        float* hprev = h1a;
        float* hnext = h1b;
        for (int t = 0; t < 12; ++t) {
            conv_down_k4<8><<<dim3(16, 8, 8), 256, 0, stream>>>(
                input + (size_t)t * 16384, 196608L, c1_w, c1_b, xt1,
                1, 128, 128, 64, 64, 64, 4);
            gru_conv5<2, 2><<<dim3(4, 16, 8), 256, 0, stream>>>(
                xt1, hprev, g1zr_w, g1zr_b, hprev, nullptr, z1, rh1,
                64, 64, 64, 2, 0);
            float* hdst = (t == 11) ? out1 : hnext;
            gru_conv5<1, 2><<<dim3(8, 8, 8), 256, 0, stream>>>(
                xt1, rh1, g1h_w, g1h_b, hprev, z1, hdst, nullptr,
                64, 64, 64, 2, 1);
            conv_down_k4<8><<<dim3(4, 16, 8), 256, 0, stream>>>(
                hdst, 262144L, c2_w, c2_b, xt2 + (size_t)t * 1048576,
                64, 64, 64, 128, 32, 32, 2);
            float* tmp = hprev; hprev = hdst; hnext = tmp;
        }
    }

    // ---- stage 2 (GRU at 32x32, C=128), conv3 fused into loop ----
    {
        float* hprev = h2a;
        float* hnext = h2b;
        for (int t = 0; t < 12; ++t) {
            const float* xt = xt2 + (size_t)t * 1048576;
            gru_conv5<1, 2><<<dim3(2, 32, 8), 256, 0, stream>>>(
                xt, hprev, g2zr_w, g2zr_b, hprev, nullptr, z2, rh2,
                128, 32, 32, 1, 0);
            float* hdst = (t == 11) ? out2 : hnext;
            gru_conv5<1, 2><<<dim3(2, 16, 8), 256, 0, stream>>>(
                xt, rh2, g2h_w, g2h_b, hprev, z2, hdst, nullptr,
                128, 32, 32, 1, 1);
            conv_down_k4<8><<<dim3(1, 16, 8), 256, 0, stream>>>(
                hdst, 131072L, c3_w, c3_b, xt3 + (size_t)t * 262144,
                128, 32, 32, 128, 16, 16, 1);
            float* tmp = hprev; hprev = hdst; hnext = tmp;
        }
    }

    // ---- stage 3 (GRU at 16x16, C=128) ----
    {
        float* hprev = h3a;
        float* hnext = h3b;
        for (int t = 0; t < 12; ++t) {
            const float* xt = xt3 + (size_t)t * 262144;
            gru_conv5<1, 1><<<dim3(1, 32, 8), 256, 0, stream>>>(
                xt, hprev, g3zr_w, g3zr_b, hprev, nullptr, z3, rh3,
                128, 16, 16, 1, 0);
            float* hdst = (t == 11) ? out3 : hnext;
            gru_conv5<1, 1><<<dim3(1, 16, 8), 256, 0, stream>>>(
                xt, rh3, g3h_w, g3h_b, hprev, z3, hdst, nullptr,
                128, 16, 16, 1, 1);
            float* tmp = hprev; hprev = hdst; hnext = tmp;
        }
    }
}

// Round 3
// 23143.591 us; speedup vs baseline: 3.1736x; 3.1736x over previous
//
#include <hip/hip_runtime.h>
#include <math.h>

typedef __attribute__((ext_vector_type(8))) short short8;
typedef __attribute__((ext_vector_type(4))) float f32x4;

static __device__ __forceinline__ float sigmoid_f(float x) { return 1.0f / (1.0f + expf(-x)); }

// exact split: x == hi_f + lo_f in fp32; hi/lo are bf16 bit patterns (hi truncated)
static __device__ __forceinline__ void split2(float x, short& hi, short& lo) {
    unsigned u = __builtin_bit_cast(unsigned, x);
    hi = (short)(u >> 16);
    float hif = __builtin_bit_cast(float, u & 0xffff0000u);
    float lof = x - hif;
    lo = (short)(__builtin_bit_cast(unsigned, lof) >> 16);
}

// ---------------------------------------------------------------------------
// Tap-decomposed implicit-GEMM conv, bf16 MFMA (3-term hi/lo product:
// xh*wh + xl*wh + xh*wl, error ~2^-18), fp32 accumulate, NO LDS.
// Activations NHWC fp32: A[b][pix][c].  Concat channels: [0,C1)=A1, [C1,..)=A2.
// Weights pre-split bf16: Wt/Wtl [tap][oc][ic]  (hi / lo planes).
// Block = 256 thr = 4 waves; block tile M=64 pixels x N=64 ocs.
// A-frag: lane&15 = pixel, k = (lane>>4)*8 + j ; B-frag: lane&15 = oc, same k.
// D-frag: col(oc)=lane&15, row(pixel)=(lane>>4)*4+reg   [HW-verified layouts]
// mode 0: zr  -> z = sigmoid(a) (oc<C), rh = sigmoid(a)*h (oc>=C)
// mode 1: h~  -> out = (1-z)*h + z*tanh(a)
// mode 2: plain conv + bias
// ---------------------------------------------------------------------------
template <int KH, int KW>
__global__ __launch_bounds__(256) void gemm_conv(
    const float* __restrict__ A1, int C1,
    const float* __restrict__ A2, int C2,
    const unsigned short* __restrict__ Wt, const unsigned short* __restrict__ Wtl,
    const float* __restrict__ bias,
    const float* __restrict__ hbuf, const float* __restrict__ zbuf,
    float* __restrict__ out1, float* __restrict__ out2,
    int Hin, int Win, int Hout, int wshift, int OC, int stride, int pad, int mode)
{
    const int K    = C1 + C2;
    const int b    = blockIdx.z;
    const int nb   = blockIdx.y;
    const int Wout = 1 << wshift;
    const int HWout = Hout << wshift;
    const int HWin  = Hin * Win;
    const int tid  = threadIdx.x;
    const int lane = tid & 63;
    const int wave = tid >> 6;
    const int pixbase = blockIdx.x * 64;

    const int apix  = pixbase + wave * 16 + (lane & 15);
    const int ay    = apix >> wshift;
    const int ax    = apix & (Wout - 1);
    const int klane = (lane >> 4) * 8;

    const float* a1b = A1 + (size_t)b * HWin * C1 + klane;
    const float* a2b = (C2 > 0) ? (A2 + (size_t)b * HWin * C2 + klane) : nullptr;

    size_t woff[4];
#pragma unroll
    for (int j = 0; j < 4; ++j) {
        int oc  = nb * 64 + j * 16 + (lane & 15);
        woff[j] = (size_t)oc * K + klane;
    }

    f32x4 acc[4] = {};

    for (int tap = 0; tap < KH * KW; ++tap) {
        const int ky = tap / KW, kx = tap - ky * KW;
        const int iy = ay * stride - pad + ky;
        const int ix = ax * stride - pad + kx;
        const bool av = ((unsigned)iy < (unsigned)Hin) && ((unsigned)ix < (unsigned)Win);
        const int ipix = av ? iy * Win + ix : 0;
        const float* a1p = a1b + (size_t)ipix * C1;
        const float* a2p = a2b ? (a2b + (size_t)ipix * C2) : nullptr;
        const size_t wtbase = (size_t)tap * OC * K;
        const unsigned short* wtap  = Wt  + wtbase;
        const unsigned short* wtapl = Wtl + wtbase;

        for (int k0 = 0; k0 < K; k0 += 32) {
            const float* ap = (k0 < C1) ? (a1p + k0) : (a2p + (k0 - C1));
            float4 x0, x1;
            if (av) {
                x0 = *(const float4*)ap;
                x1 = *(const float4*)(ap + 4);
            } else {
                x0 = make_float4(0.f, 0.f, 0.f, 0.f);
                x1 = x0;
            }
            float xs[8] = {x0.x, x0.y, x0.z, x0.w, x1.x, x1.y, x1.z, x1.w};
            short8 ahi, alo;
#pragma unroll
            for (int e = 0; e < 8; ++e) { short h, l; split2(xs[e], h, l); ahi[e] = h; alo[e] = l; }
#pragma unroll
            for (int j = 0; j < 4; ++j) {
                short8 bh = *(const short8*)(wtap  + woff[j] + k0);
                short8 bl = *(const short8*)(wtapl + woff[j] + k0);
                acc[j] = __builtin_amdgcn_mfma_f32_16x16x32_bf16(ahi, bh, acc[j], 0, 0, 0);
                acc[j] = __builtin_amdgcn_mfma_f32_16x16x32_bf16(alo, bh, acc[j], 0, 0, 0);
                acc[j] = __builtin_amdgcn_mfma_f32_16x16x32_bf16(ahi, bl, acc[j], 0, 0, 0);
            }
        }
    }

    const int prow = pixbase + wave * 16 + ((lane >> 4) << 2);
#pragma unroll
    for (int j = 0; j < 4; ++j) {
        const int oc = nb * 64 + j * 16 + (lane & 15);
        const float bv = bias[oc];
#pragma unroll
        for (int r = 0; r < 4; ++r) {
            const int pix = prow + r;
            float a = acc[j][r] + bv;
            const size_t pbase = (size_t)b * HWout + pix;
            if (mode == 0) {
                const int Ch = OC >> 1;
                float s = sigmoid_f(a);
                if (oc < Ch) {
                    out1[pbase * Ch + oc] = s;
                } else {
                    size_t idx = pbase * Ch + (oc - Ch);
                    out2[idx] = s * hbuf[idx];
                }
            } else if (mode == 1) {
                size_t idx = pbase * OC + oc;
                float zv = zbuf[idx], hv = hbuf[idx];
                out1[idx] = (1.f - zv) * hv + zv * tanhf(a);
            } else {
                out1[pbase * OC + oc] = a;
            }
        }
    }
}

// ---------------------------------------------------------------------------
// conv1: IC=1, k4 s2 p1, 128x128 -> 64x64, OC=64.  Direct fp32, NHWC output.
// ---------------------------------------------------------------------------
__global__ __launch_bounds__(256) void conv1_k(
    const float* __restrict__ in, const float* __restrict__ w,
    const float* __restrict__ bias, float* __restrict__ out)
{
    const int b   = blockIdx.y;
    const int tid = threadIdx.x;
    const int px  = blockIdx.x * 64 + (tid & 63);
    const int ocg = tid >> 6;
    const int y = px >> 6, x = px & 63;
    const float* src = in + (size_t)b * 196608;
    float v[16];
#pragma unroll
    for (int ky = 0; ky < 4; ++ky)
#pragma unroll
        for (int kx = 0; kx < 4; ++kx) {
            int iy = 2 * y - 1 + ky, ix = 2 * x - 1 + kx;
            v[ky * 4 + kx] = ((unsigned)iy < 128u && (unsigned)ix < 128u) ? src[iy * 128 + ix] : 0.f;
        }
    float* op = out + ((size_t)b * 4096 + px) * 64 + ocg * 16;
#pragma unroll
    for (int o = 0; o < 16; ++o) {
        int oc = ocg * 16 + o;
        float s = bias[oc];
        const float* wr = w + oc * 16;
#pragma unroll
        for (int t = 0; t < 16; ++t) s += wr[t] * v[t];
        op[o] = s;
    }
}

// w[oc][ic][kh][kw] fp32 -> wt_hi/wt_lo [tap][oc][ic] bf16 (exact hi/lo split)
__global__ __launch_bounds__(256) void prep_w(
    const float* __restrict__ w, unsigned short* __restrict__ wt_hi,
    unsigned short* __restrict__ wt_lo, int OC, int IC, int KK)
{
    int i = blockIdx.x * 256 + threadIdx.x;
    int total = OC * IC * KK;
    if (i >= total) return;
    int oc = i / (IC * KK);
    int r  = i - oc * (IC * KK);
    int ic = r / KK;
    int tap = r - ic * KK;
    float x = w[i];
    short h, l;
    split2(x, h, l);
    size_t o = ((size_t)tap * OC + oc) * IC + ic;
    wt_hi[o] = (unsigned short)h;
    wt_lo[o] = (unsigned short)l;
}

// NHWC [8][HW][C] -> NCHW [8][C][HW]
__global__ __launch_bounds__(256) void nhwc_to_nchw(
    const float* __restrict__ src, float* __restrict__ dst, int C, int HW)
{
    int i = blockIdx.x * 256 + threadIdx.x;
    int b = i / (C * HW);
    int r = i - b * (C * HW);
    int c = r / HW;
    int p = r - c * HW;
    dst[i] = src[((size_t)b * HW + p) * C + c];
}

// ---------------------------------------------------------------------------
extern "C" void kernel_launch(void* const* d_in, const int* in_sizes, int n_in,
                              void* d_out, int out_size, void* d_ws, size_t ws_size,
                              hipStream_t stream)
{
    (void)in_sizes; (void)n_in; (void)out_size; (void)ws_size;

    const float* input  = (const float*)d_in[0];
    const float* c1_w   = (const float*)d_in[1];
    const float* c1_b   = (const float*)d_in[2];
    const float* g1zr_w = (const float*)d_in[3];
    const float* g1zr_b = (const float*)d_in[4];
    const float* g1h_w  = (const float*)d_in[5];
    const float* g1h_b  = (const float*)d_in[6];
    const float* c2_w   = (const float*)d_in[7];
    const float* c2_b   = (const float*)d_in[8];
    const float* g2zr_w = (const float*)d_in[9];
    const float* g2zr_b = (const float*)d_in[10];
    const float* g2h_w  = (const float*)d_in[11];
    const float* g2h_b  = (const float*)d_in[12];
    const float* c3_w   = (const float*)d_in[13];
    const float* c3_b   = (const float*)d_in[14];
    const float* g3zr_w = (const float*)d_in[15];
    const float* g3zr_b = (const float*)d_in[16];
    const float* g3h_w  = (const float*)d_in[17];
    const float* g3h_b  = (const float*)d_in[18];

    float* out1 = (float*)d_out;                 // [8,64,64,64]  NCHW
    float* out2 = (float*)d_out + 2097152;       // [8,128,32,32]
    float* out3 = (float*)d_out + 3145728;       // [8,128,16,16]

    char* ws = (char*)d_ws;
    size_t off = 0;
    auto takeB = [&](size_t bytes) { char* p = ws + off; off += (bytes + 255) & ~(size_t)255; return p; };

    auto takeW = [&](size_t elems) {
        unsigned short* hi = (unsigned short*)takeB(elems * 2);
        unsigned short* lo = (unsigned short*)takeB(elems * 2);
        return (void*)0, hi, lo;  // dummy
    };
    (void)takeW;

    unsigned short* wt_g1zr   = (unsigned short*)takeB(25 * 128 * 128 * 2);
    unsigned short* wt_g1zr_l = (unsigned short*)takeB(25 * 128 * 128 * 2);
    unsigned short* wt_g1h    = (unsigned short*)takeB(25 * 64 * 128 * 2);
    unsigned short* wt_g1h_l  = (unsigned short*)takeB(25 * 64 * 128 * 2);
    unsigned short* wt_c2     = (unsigned short*)takeB(16 * 128 * 64 * 2);
    unsigned short* wt_c2_l   = (unsigned short*)takeB(16 * 128 * 64 * 2);
    unsigned short* wt_g2zr   = (unsigned short*)takeB(25 * 256 * 256 * 2);
    unsigned short* wt_g2zr_l = (unsigned short*)takeB(25 * 256 * 256 * 2);
    unsigned short* wt_g2h    = (unsigned short*)takeB(25 * 128 * 256 * 2);
    unsigned short* wt_g2h_l  = (unsigned short*)takeB(25 * 128 * 256 * 2);
    unsigned short* wt_c3     = (unsigned short*)takeB(16 * 128 * 128 * 2);
    unsigned short* wt_c3_l   = (unsigned short*)takeB(16 * 128 * 128 * 2);
    unsigned short* wt_g3zr   = (unsigned short*)takeB(25 * 256 * 256 * 2);
    unsigned short* wt_g3zr_l = (unsigned short*)takeB(25 * 256 * 256 * 2);
    unsigned short* wt_g3h    = (unsigned short*)takeB(25 * 128 * 256 * 2);
    unsigned short* wt_g3h_l  = (unsigned short*)takeB(25 * 128 * 256 * 2);

    float* xt1  = (float*)takeB(8388608);   // [8,4096,64]
    float* h1a  = (float*)takeB(8388608);
    float* h1b  = (float*)takeB(8388608);
    float* z1   = (float*)takeB(8388608);
    float* rh1  = (float*)takeB(8388608);
    float* xt2  = (float*)takeB(4194304);   // [8,1024,128]
    float* h2a  = (float*)takeB(4194304);
    float* h2b  = (float*)takeB(4194304);
    float* z2   = (float*)takeB(4194304);
    float* rh2  = (float*)takeB(4194304);
    float* xt3  = (float*)takeB(1048576);   // [8,256,128]
    float* h3a  = (float*)takeB(1048576);
    float* h3b  = (float*)takeB(1048576);
    float* z3   = (float*)takeB(1048576);
    float* rh3  = (float*)takeB(1048576);
    float* zeros = (float*)takeB(8388608);

    hipMemsetAsync(zeros, 0, 8388608, stream);

    auto prep = [&](const float* w, unsigned short* hi, unsigned short* lo,
                    int OC, int IC, int KK) {
        int total = OC * IC * KK;
        prep_w<<<(total + 255) / 256, 256, 0, stream>>>(w, hi, lo, OC, IC, KK);
    };
    prep(g1zr_w, wt_g1zr, wt_g1zr_l, 128, 128, 25);
    prep(g1h_w,  wt_g1h,  wt_g1h_l,  64, 128, 25);
    prep(c2_w,   wt_c2,   wt_c2_l,   128, 64, 16);
    prep(g2zr_w, wt_g2zr, wt_g2zr_l, 256, 256, 25);
    prep(g2h_w,  wt_g2h,  wt_g2h_l,  128, 256, 25);
    prep(c3_w,   wt_c3,   wt_c3_l,   128, 128, 16);
    prep(g3zr_w, wt_g3zr, wt_g3zr_l, 256, 256, 25);
    prep(g3h_w,  wt_g3h,  wt_g3h_l,  128, 256, 25);

    float* h1buf[2] = {h1a, h1b};
    float* h2buf[2] = {h2a, h2b};
    float* h3buf[2] = {h3a, h3b};

    for (int t = 0; t < 12; ++t) {
        const float* hp1 = (t == 0) ? zeros : h1buf[(t - 1) & 1];
        const float* hp2 = (t == 0) ? zeros : h2buf[(t - 1) & 1];
        const float* hp3 = (t == 0) ? zeros : h3buf[(t - 1) & 1];
        float* hd1 = h1buf[t & 1];
        float* hd2 = h2buf[t & 1];
        float* hd3 = h3buf[t & 1];

        conv1_k<<<dim3(64, 8), 256, 0, stream>>>(input + (size_t)t * 16384, c1_w, c1_b, xt1);

        gemm_conv<5, 5><<<dim3(64, 2, 8), 256, 0, stream>>>(
            xt1, 64, hp1, 64, wt_g1zr, wt_g1zr_l, g1zr_b, hp1, nullptr, z1, rh1,
            64, 64, 64, 6, 128, 1, 2, 0);
        gemm_conv<5, 5><<<dim3(64, 1, 8), 256, 0, stream>>>(
            xt1, 64, rh1, 64, wt_g1h, wt_g1h_l, g1h_b, hp1, z1, hd1, nullptr,
            64, 64, 64, 6, 64, 1, 2, 1);

        gemm_conv<4, 4><<<dim3(16, 2, 8), 256, 0, stream>>>(
            hd1, 64, nullptr, 0, wt_c2, wt_c2_l, c2_b, nullptr, nullptr, xt2, nullptr,
            64, 64, 32, 5, 128, 2, 1, 2);

        gemm_conv<5, 5><<<dim3(16, 4, 8), 256, 0, stream>>>(
            xt2, 128, hp2, 128, wt_g2zr, wt_g2zr_l, g2zr_b, hp2, nullptr, z2, rh2,
            32, 32, 32, 5, 256, 1, 2, 0);
        gemm_conv<5, 5><<<dim3(16, 2, 8), 256, 0, stream>>>(
            xt2, 128, rh2, 128, wt_g2h, wt_g2h_l, g2h_b, hp2, z2, hd2, nullptr,
            32, 32, 32, 5, 128, 1, 2, 1);

        gemm_conv<4, 4><<<dim3(4, 2, 8), 256, 0, stream>>>(
            hd2, 128, nullptr, 0, wt_c3, wt_c3_l, c3_b, nullptr, nullptr, xt3, nullptr,
            32, 32, 16, 4, 128, 2, 1, 2);

        gemm_conv<5, 5><<<dim3(4, 4, 8), 256, 0, stream>>>(
            xt3, 128, hp3, 128, wt_g3zr, wt_g3zr_l, g3zr_b, hp3, nullptr, z3, rh3,
            16, 16, 16, 4, 256, 1, 2, 0);
        gemm_conv<5, 5><<<dim3(4, 2, 8), 256, 0, stream>>>(
            xt3, 128, rh3, 128, wt_g3h, wt_g3h_l, g3h_b, hp3, z3, hd3, nullptr,
            16, 16, 16, 4, 128, 1, 2, 1);
    }

    nhwc_to_nchw<<<8192, 256, 0, stream>>>(h1buf[1], out1, 64, 4096);
    nhwc_to_nchw<<<4096, 256, 0, stream>>>(h2buf[1], out2, 128, 1024);
    nhwc_to_nchw<<<1024, 256, 0, stream>>>(h3buf[1], out3, 128, 256);
}

// Round 4
// 22488.283 us; speedup vs baseline: 3.2661x; 1.0291x over previous
//
#include <hip/hip_runtime.h>
#include <math.h>

typedef __attribute__((ext_vector_type(8))) short short8;
typedef __attribute__((ext_vector_type(4))) float f32x4;

static __device__ __forceinline__ float sigmoid_f(float x) { return 1.0f / (1.0f + expf(-x)); }

// exact split: x == hi_f + lo_f in fp32; hi/lo are bf16 bit patterns (hi truncated)
static __device__ __forceinline__ void split2(float x, unsigned short& hi, unsigned short& lo) {
    unsigned u = __builtin_bit_cast(unsigned, x);
    hi = (unsigned short)(u >> 16);
    float hif = __builtin_bit_cast(float, u & 0xffff0000u);
    float lof = x - hif;
    lo = (unsigned short)(__builtin_bit_cast(unsigned, lof) >> 16);
}

static __device__ __forceinline__ float bf2f(unsigned short u) {
    return __builtin_bit_cast(float, ((unsigned)u) << 16);
}

// ---------------------------------------------------------------------------
// Tap-decomposed implicit-GEMM conv, bf16 MFMA, 3-term hi/lo product
// (xh*wh + xl*wh + xh*wl), fp32 accumulate, NO LDS, NO barriers.
// Activations: pre-split bf16 hi/lo planes, NHWC with channel stride CS and
// window offset koff (per-stage layout [h | xt | rh], each C channels).
// Weights pre-split bf16 [tap][oc][ic].
// Block = 256 thr = 4 waves; wave owns 32 px x 64 oc (2 A-groups x 4 B-frags,
// 8 acc frags, 24 MFMAs per 32-wide k-step vs 12 x 16B loads).
// A-frag: lane&15=pixel, k=(lane>>4)*8+j ; B-frag: lane&15=oc, same k.
// D-frag: col(oc)=lane&15, row(pixel)=(lane>>4)*4+reg  [HW-verified layouts]
// MODE 0: zr  -> z=sigmoid(a) fp32 (oc<C) ; rh=sigmoid(a)*h -> cat[2C+..] hi/lo
// MODE 1: h~  -> h' = (1-z)*h + z*tanh(a) -> cat[0..C) hi/lo
// MODE 2: conv+bias -> next-stage cat xt region hi/lo
// ---------------------------------------------------------------------------
template <int KH, int KW, int K, int MODE>
__global__ __launch_bounds__(256) void gemm_conv(
    const unsigned short* __restrict__ Ah, const unsigned short* __restrict__ Al,
    int CS, int koff,
    const unsigned short* __restrict__ Wh, const unsigned short* __restrict__ Wl,
    const float* __restrict__ bias,
    const float* __restrict__ zbuf, float* __restrict__ zout,
    unsigned short* __restrict__ Oh, unsigned short* __restrict__ Ol,
    int OCS, int okoff,
    int Hin, int Win, int Hout, int wshift, int OC, int stride, int pad)
{
    const int b    = blockIdx.z;
    const int nb   = blockIdx.y;
    const int Wout = 1 << wshift;
    const int HWin = Hin * Win;
    const int HWout = Hout << wshift;
    const int lane = threadIdx.x & 63;
    const int wave = threadIdx.x >> 6;
    const int pixbase = blockIdx.x * 128 + wave * 32;
    const int klane = (lane >> 4) * 8;

    int apix[2];
    apix[0] = pixbase + (lane & 15);
    apix[1] = apix[0] + 16;

    size_t woff[4];
#pragma unroll
    for (int j = 0; j < 4; ++j) {
        int oc  = nb * 64 + j * 16 + (lane & 15);
        woff[j] = (size_t)oc * K + klane;
    }

    f32x4 acc[2][4] = {};

    const size_t bbase = (size_t)b * HWin;

#pragma unroll 1
    for (int tap = 0; tap < KH * KW; ++tap) {
        const int ky = tap / KW, kx = tap - ky * KW;
        size_t abase[2];
        bool av[2];
#pragma unroll
        for (int g = 0; g < 2; ++g) {
            int ay = apix[g] >> wshift;
            int ax = apix[g] & (Wout - 1);
            int iy = ay * stride - pad + ky;
            int ix = ax * stride - pad + kx;
            av[g] = ((unsigned)iy < (unsigned)Hin) && ((unsigned)ix < (unsigned)Win);
            int ipix = av[g] ? iy * Win + ix : 0;
            abase[g] = (bbase + ipix) * CS + koff + klane;
        }
        const size_t wtb = (size_t)tap * OC * K;
        const unsigned short* wth = Wh + wtb;
        const unsigned short* wtl = Wl + wtb;

        const short8 zero8 = {0, 0, 0, 0, 0, 0, 0, 0};
#pragma unroll
        for (int k0 = 0; k0 < K; k0 += 32) {
            short8 a0h = av[0] ? *(const short8*)(Ah + abase[0] + k0) : zero8;
            short8 a0l = av[0] ? *(const short8*)(Al + abase[0] + k0) : zero8;
            short8 a1h = av[1] ? *(const short8*)(Ah + abase[1] + k0) : zero8;
            short8 a1l = av[1] ? *(const short8*)(Al + abase[1] + k0) : zero8;
#pragma unroll
            for (int j = 0; j < 4; ++j) {
                short8 bh = *(const short8*)(wth + woff[j] + k0);
                short8 bl = *(const short8*)(wtl + woff[j] + k0);
                acc[0][j] = __builtin_amdgcn_mfma_f32_16x16x32_bf16(a0h, bh, acc[0][j], 0, 0, 0);
                acc[0][j] = __builtin_amdgcn_mfma_f32_16x16x32_bf16(a0l, bh, acc[0][j], 0, 0, 0);
                acc[0][j] = __builtin_amdgcn_mfma_f32_16x16x32_bf16(a0h, bl, acc[0][j], 0, 0, 0);
                acc[1][j] = __builtin_amdgcn_mfma_f32_16x16x32_bf16(a1h, bh, acc[1][j], 0, 0, 0);
                acc[1][j] = __builtin_amdgcn_mfma_f32_16x16x32_bf16(a1l, bh, acc[1][j], 0, 0, 0);
                acc[1][j] = __builtin_amdgcn_mfma_f32_16x16x32_bf16(a1h, bl, acc[1][j], 0, 0, 0);
            }
        }
    }

    // epilogue
    const int Cc = (MODE == 0) ? (OC >> 1) : OC;
#pragma unroll
    for (int g = 0; g < 2; ++g) {
#pragma unroll
        for (int j = 0; j < 4; ++j) {
            const int oc = nb * 64 + j * 16 + (lane & 15);
            const float bv = bias[oc];
#pragma unroll
            for (int r = 0; r < 4; ++r) {
                const int pix = pixbase + 16 * g + ((lane >> 4) << 2) + r;
                const size_t pbase = (size_t)b * HWout + pix;
                float a = acc[g][j][r] + bv;
                if (MODE == 0) {
                    float s = sigmoid_f(a);
                    if (oc < Cc) {
                        zout[pbase * Cc + oc] = s;
                    } else {
                        // h from cat ch[0,Cc): exact fp32 = hi + lo
                        size_t hidx = pbase * CS + (oc - Cc);
                        float hv = bf2f(Ah[hidx]) + bf2f(Al[hidx]);
                        float rh = s * hv;
                        unsigned short hi, lo;
                        split2(rh, hi, lo);
                        size_t oidx = pbase * CS + Cc + oc;  // = 2C + (oc-C)
                        Oh[oidx] = hi; Ol[oidx] = lo;
                    }
                } else if (MODE == 1) {
                    size_t hidx = pbase * CS + oc;
                    float hv = bf2f(Ah[hidx]) + bf2f(Al[hidx]);
                    float zv = zbuf[pbase * Cc + oc];
                    float hn = (1.f - zv) * hv + zv * tanhf(a);
                    unsigned short hi, lo;
                    split2(hn, hi, lo);
                    Oh[hidx] = hi; Ol[hidx] = lo;
                } else {
                    unsigned short hi, lo;
                    split2(a, hi, lo);
                    size_t oidx = pbase * OCS + okoff + oc;
                    Oh[oidx] = hi; Ol[oidx] = lo;
                }
            }
        }
    }
}

// ---------------------------------------------------------------------------
// conv1: IC=1, k4 s2 p1, 128x128 -> 64x64, OC=64.  Direct fp32, writes bf16
// hi/lo into cat1 xt region (channels [64,128), CS=192).
// ---------------------------------------------------------------------------
__global__ __launch_bounds__(256) void conv1_k(
    const float* __restrict__ in, const float* __restrict__ w,
    const float* __restrict__ bias,
    unsigned short* __restrict__ Oh, unsigned short* __restrict__ Ol)
{
    const int b   = blockIdx.y;
    const int tid = threadIdx.x;
    const int px  = blockIdx.x * 64 + (tid & 63);
    const int ocg = tid >> 6;
    const int y = px >> 6, x = px & 63;
    const float* src = in + (size_t)b * 196608;
    float v[16];
#pragma unroll
    for (int ky = 0; ky < 4; ++ky)
#pragma unroll
        for (int kx = 0; kx < 4; ++kx) {
            int iy = 2 * y - 1 + ky, ix = 2 * x - 1 + kx;
            v[ky * 4 + kx] = ((unsigned)iy < 128u && (unsigned)ix < 128u) ? src[iy * 128 + ix] : 0.f;
        }
    size_t obase = ((size_t)b * 4096 + px) * 192 + 64 + ocg * 16;
#pragma unroll
    for (int o = 0; o < 16; ++o) {
        int oc = ocg * 16 + o;
        float s = bias[oc];
        const float* wr = w + oc * 16;
#pragma unroll
        for (int t = 0; t < 16; ++t) s += wr[t] * v[t];
        unsigned short hi, lo;
        split2(s, hi, lo);
        Oh[obase + o] = hi; Ol[obase + o] = lo;
    }
}

// w[oc][ic][kh][kw] fp32 -> wt_hi/wt_lo [tap][oc][ic'] bf16 (exact split).
// perm=1: swap input-channel halves (zr convs: ref concat [x,h] -> cat [h,xt]).
__global__ __launch_bounds__(256) void prep_w(
    const float* __restrict__ w, unsigned short* __restrict__ wt_hi,
    unsigned short* __restrict__ wt_lo, int OC, int IC, int KK, int perm)
{
    int i = blockIdx.x * 256 + threadIdx.x;
    int total = OC * IC * KK;
    if (i >= total) return;
    int oc = i / (IC * KK);
    int r  = i - oc * (IC * KK);
    int ic = r / KK;
    int tap = r - ic * KK;
    int icn = perm ? ((ic < IC / 2) ? ic + IC / 2 : ic - IC / 2) : ic;
    unsigned short h, l;
    split2(w[i], h, l);
    size_t o = ((size_t)tap * OC + oc) * IC + icn;
    wt_hi[o] = h;
    wt_lo[o] = l;
}

// cat hi/lo h-region -> fp32 NCHW
__global__ __launch_bounds__(256) void cat_to_nchw(
    const unsigned short* __restrict__ hi, const unsigned short* __restrict__ lo,
    float* __restrict__ dst, int C, int HW, int CS)
{
    int i = blockIdx.x * 256 + threadIdx.x;
    int b = i / (C * HW);
    int r = i - b * (C * HW);
    int c = r / HW;
    int p = r - c * HW;
    size_t s = ((size_t)b * HW + p) * CS + c;
    dst[i] = bf2f(hi[s]) + bf2f(lo[s]);
}

// ---------------------------------------------------------------------------
extern "C" void kernel_launch(void* const* d_in, const int* in_sizes, int n_in,
                              void* d_out, int out_size, void* d_ws, size_t ws_size,
                              hipStream_t stream)
{
    (void)in_sizes; (void)n_in; (void)out_size; (void)ws_size;

    const float* input  = (const float*)d_in[0];
    const float* c1_w   = (const float*)d_in[1];
    const float* c1_b   = (const float*)d_in[2];
    const float* g1zr_w = (const float*)d_in[3];
    const float* g1zr_b = (const float*)d_in[4];
    const float* g1h_w  = (const float*)d_in[5];
    const float* g1h_b  = (const float*)d_in[6];
    const float* c2_w   = (const float*)d_in[7];
    const float* c2_b   = (const float*)d_in[8];
    const float* g2zr_w = (const float*)d_in[9];
    const float* g2zr_b = (const float*)d_in[10];
    const float* g2h_w  = (const float*)d_in[11];
    const float* g2h_b  = (const float*)d_in[12];
    const float* c3_w   = (const float*)d_in[13];
    const float* c3_b   = (const float*)d_in[14];
    const float* g3zr_w = (const float*)d_in[15];
    const float* g3zr_b = (const float*)d_in[16];
    const float* g3h_w  = (const float*)d_in[17];
    const float* g3h_b  = (const float*)d_in[18];

    float* out1 = (float*)d_out;                 // [8,64,64,64]  NCHW
    float* out2 = (float*)d_out + 2097152;       // [8,128,32,32]
    float* out3 = (float*)d_out + 3145728;       // [8,128,16,16]

    char* ws = (char*)d_ws;
    size_t off = 0;
    auto takeB = [&](size_t bytes) { char* p = ws + off; off += (bytes + 255) & ~(size_t)255; return p; };

    unsigned short* wt_g1zr   = (unsigned short*)takeB(25 * 128 * 128 * 2);
    unsigned short* wt_g1zr_l = (unsigned short*)takeB(25 * 128 * 128 * 2);
    unsigned short* wt_g1h    = (unsigned short*)takeB(25 * 64 * 128 * 2);
    unsigned short* wt_g1h_l  = (unsigned short*)takeB(25 * 64 * 128 * 2);
    unsigned short* wt_c2     = (unsigned short*)takeB(16 * 128 * 64 * 2);
    unsigned short* wt_c2_l   = (unsigned short*)takeB(16 * 128 * 64 * 2);
    unsigned short* wt_g2zr   = (unsigned short*)takeB(25 * 256 * 256 * 2);
    unsigned short* wt_g2zr_l = (unsigned short*)takeB(25 * 256 * 256 * 2);
    unsigned short* wt_g2h    = (unsigned short*)takeB(25 * 128 * 256 * 2);
    unsigned short* wt_g2h_l  = (unsigned short*)takeB(25 * 128 * 256 * 2);
    unsigned short* wt_c3     = (unsigned short*)takeB(16 * 128 * 128 * 2);
    unsigned short* wt_c3_l   = (unsigned short*)takeB(16 * 128 * 128 * 2);
    unsigned short* wt_g3zr   = (unsigned short*)takeB(25 * 256 * 256 * 2);
    unsigned short* wt_g3zr_l = (unsigned short*)takeB(25 * 256 * 256 * 2);
    unsigned short* wt_g3h    = (unsigned short*)takeB(25 * 128 * 256 * 2);
    unsigned short* wt_g3h_l  = (unsigned short*)takeB(25 * 128 * 256 * 2);

    // stage cat buffers: layout [h | xt | rh], each C channels, bf16 hi/lo
    const size_t cat1_n = (size_t)8 * 4096 * 192;  // C=64,  CS=192
    const size_t cat2_n = (size_t)8 * 1024 * 384;  // C=128, CS=384
    const size_t cat3_n = (size_t)8 * 256 * 384;   // C=128, CS=384
    unsigned short* cat1h = (unsigned short*)takeB(cat1_n * 2);
    unsigned short* cat1l = (unsigned short*)takeB(cat1_n * 2);
    unsigned short* cat2h = (unsigned short*)takeB(cat2_n * 2);
    unsigned short* cat2l = (unsigned short*)takeB(cat2_n * 2);
    unsigned short* cat3h = (unsigned short*)takeB(cat3_n * 2);
    unsigned short* cat3l = (unsigned short*)takeB(cat3_n * 2);
    float* z1 = (float*)takeB((size_t)8 * 4096 * 64 * 4);
    float* z2 = (float*)takeB((size_t)8 * 1024 * 128 * 4);
    float* z3 = (float*)takeB((size_t)8 * 256 * 128 * 4);

    // zero h regions (whole cats for simplicity; every call identical)
    hipMemsetAsync(cat1h, 0, cat1_n * 2, stream);
    hipMemsetAsync(cat1l, 0, cat1_n * 2, stream);
    hipMemsetAsync(cat2h, 0, cat2_n * 2, stream);
    hipMemsetAsync(cat2l, 0, cat2_n * 2, stream);
    hipMemsetAsync(cat3h, 0, cat3_n * 2, stream);
    hipMemsetAsync(cat3l, 0, cat3_n * 2, stream);

    auto prep = [&](const float* w, unsigned short* hi, unsigned short* lo,
                    int OC, int IC, int KK, int perm) {
        int total = OC * IC * KK;
        prep_w<<<(total + 255) / 256, 256, 0, stream>>>(w, hi, lo, OC, IC, KK, perm);
    };
    prep(g1zr_w, wt_g1zr, wt_g1zr_l, 128, 128, 25, 1);
    prep(g1h_w,  wt_g1h,  wt_g1h_l,  64, 128, 25, 0);
    prep(c2_w,   wt_c2,   wt_c2_l,   128, 64, 16, 0);
    prep(g2zr_w, wt_g2zr, wt_g2zr_l, 256, 256, 25, 1);
    prep(g2h_w,  wt_g2h,  wt_g2h_l,  128, 256, 25, 0);
    prep(c3_w,   wt_c3,   wt_c3_l,   128, 128, 16, 0);
    prep(g3zr_w, wt_g3zr, wt_g3zr_l, 256, 256, 25, 1);
    prep(g3h_w,  wt_g3h,  wt_g3h_l,  128, 256, 25, 0);

    for (int t = 0; t < 12; ++t) {
        // stage 1 @64x64, C=64, CS=192
        conv1_k<<<dim3(64, 8), 256, 0, stream>>>(
            input + (size_t)t * 16384, c1_w, c1_b, cat1h, cat1l);
        gemm_conv<5, 5, 128, 0><<<dim3(32, 2, 8), 256, 0, stream>>>(
            cat1h, cat1l, 192, 0, wt_g1zr, wt_g1zr_l, g1zr_b,
            nullptr, z1, cat1h, cat1l, 0, 0,
            64, 64, 64, 6, 128, 1, 2);
        gemm_conv<5, 5, 128, 1><<<dim3(32, 1, 8), 256, 0, stream>>>(
            cat1h, cat1l, 192, 64, wt_g1h, wt_g1h_l, g1h_b,
            z1, nullptr, cat1h, cat1l, 0, 0,
            64, 64, 64, 6, 64, 1, 2);
        // c2: reads stage-1 h (ch[0,64)), writes stage-2 xt (ch[128,256))
        gemm_conv<4, 4, 64, 2><<<dim3(8, 2, 8), 256, 0, stream>>>(
            cat1h, cat1l, 192, 0, wt_c2, wt_c2_l, c2_b,
            nullptr, nullptr, cat2h, cat2l, 384, 128,
            64, 64, 32, 5, 128, 2, 1);
        // stage 2 @32x32, C=128, CS=384
        gemm_conv<5, 5, 256, 0><<<dim3(8, 4, 8), 256, 0, stream>>>(
            cat2h, cat2l, 384, 0, wt_g2zr, wt_g2zr_l, g2zr_b,
            nullptr, z2, cat2h, cat2l, 0, 0,
            32, 32, 32, 5, 256, 1, 2);
        gemm_conv<5, 5, 256, 1><<<dim3(8, 2, 8), 256, 0, stream>>>(
            cat2h, cat2l, 384, 128, wt_g2h, wt_g2h_l, g2h_b,
            z2, nullptr, cat2h, cat2l, 0, 0,
            32, 32, 32, 5, 128, 1, 2);
        // c3: reads stage-2 h, writes stage-3 xt
        gemm_conv<4, 4, 128, 2><<<dim3(2, 2, 8), 256, 0, stream>>>(
            cat2h, cat2l, 384, 0, wt_c3, wt_c3_l, c3_b,
            nullptr, nullptr, cat3h, cat3l, 384, 128,
            32, 32, 16, 4, 128, 2, 1);
        // stage 3 @16x16, C=128, CS=384
        gemm_conv<5, 5, 256, 0><<<dim3(2, 4, 8), 256, 0, stream>>>(
            cat3h, cat3l, 384, 0, wt_g3zr, wt_g3zr_l, g3zr_b,
            nullptr, z3, cat3h, cat3l, 0, 0,
            16, 16, 16, 4, 256, 1, 2);
        gemm_conv<5, 5, 256, 1><<<dim3(2, 2, 8), 256, 0, stream>>>(
            cat3h, cat3l, 384, 128, wt_g3h, wt_g3h_l, g3h_b,
            z3, nullptr, cat3h, cat3l, 0, 0,
            16, 16, 16, 4, 128, 1, 2);
    }

    cat_to_nchw<<<8192, 256, 0, stream>>>(cat1h, cat1l, out1, 64, 4096, 192);
    cat_to_nchw<<<4096, 256, 0, stream>>>(cat2h, cat2l, out2, 128, 1024, 384);
    cat_to_nchw<<<1024, 256, 0, stream>>>(cat3h, cat3l, out3, 128, 256, 384);
}

// Round 5
// 15000.000 us; speedup vs baseline: 4.8966x; 1.4992x over previous
//
#include <hip/hip_runtime.h>
#include <math.h>

typedef _Float16 f16;
typedef __attribute__((ext_vector_type(8))) _Float16 half8;
typedef __attribute__((ext_vector_type(4))) float f32x4;

static __device__ __forceinline__ float sigmoid_f(float x) { return 1.0f / (1.0f + expf(-x)); }

// exact split: x == (float)hi + (float)lo / 4096.  lo pre-scaled by 2^12 so it
// stays in f16 normal range (robust to any denormal flushing in the MFMA).
static __device__ __forceinline__ void splitf(float x, f16& hi, f16& lo) {
    hi = (f16)x;
    float r = x - (float)hi;
    lo = (f16)(r * 4096.0f);
}

// ---------------------------------------------------------------------------
// Tap-decomposed implicit-GEMM conv, f16 MFMA, 2-term activation split
// (ah*w -> acc, al*w -> acc2, combine acc + acc2/4096), fp32 accumulate,
// NO LDS, NO barriers.  Weights single f16 plane [tap][oc][ic].
// Activations f16 hi/lo planes, NHWC, channel stride CS, window offset koff
// (per-stage cat layout [h | xt | rh], each C channels).
// Block = 4 waves; wave owns NG*16 px x 64 oc.  Per 32-wide k-step:
// NG*2 A loads + 4 B loads -> 8*NG MFMAs, ALL independent (16 distinct accs).
// A-frag: lane&15=pixel, k=(lane>>4)*8+j ; B-frag: lane&15=oc, same k.
// D-frag: col(oc)=lane&15, row(pixel)=(lane>>4)*4+reg  [HW-verified layouts]
// MODE 0: zr  -> z=sigmoid(a) fp32 (oc<C) ; rh=sigmoid(a)*h -> cat[2C..3C)
// MODE 1: h~  -> h' = (1-z)*h + z*tanh(a) -> cat[0..C)
// MODE 2: conv+bias -> next-stage cat xt region
// ---------------------------------------------------------------------------
template <int KH, int KW, int K, int MODE, int NG>
__global__ __launch_bounds__(256) void gemm_conv(
    const f16* __restrict__ Ah, const f16* __restrict__ Al,
    int CS, int koff,
    const f16* __restrict__ Wt, const float* __restrict__ bias,
    const float* __restrict__ zbuf, float* __restrict__ zout,
    f16* __restrict__ Oh, f16* __restrict__ Ol,
    int OCS, int okoff,
    int Hin, int Win, int Hout, int wshift, int OC, int stride, int pad)
{
    const int b    = blockIdx.z;
    const int nb   = blockIdx.y;
    const int Wout = 1 << wshift;
    const int HWin = Hin * Win;
    const int HWout = Hout << wshift;
    const int lane = threadIdx.x & 63;
    const int wave = threadIdx.x >> 6;
    const int pixbase = (blockIdx.x * 4 + wave) * (NG * 16);
    const int klane = (lane >> 4) * 8;

    int apix[NG];
#pragma unroll
    for (int g = 0; g < NG; ++g) apix[g] = pixbase + 16 * g + (lane & 15);

    size_t woff[4];
#pragma unroll
    for (int j = 0; j < 4; ++j) {
        int oc  = nb * 64 + j * 16 + (lane & 15);
        woff[j] = (size_t)oc * K + klane;
    }

    f32x4 acc[NG][4] = {};
    f32x4 acc2[NG][4] = {};

    const size_t bbase = (size_t)b * HWin;
    const half8 zero8 = {0, 0, 0, 0, 0, 0, 0, 0};

#pragma unroll 1
    for (int tap = 0; tap < KH * KW; ++tap) {
        const int ky = tap / KW, kx = tap - ky * KW;
        size_t abase[NG];
        bool av[NG];
#pragma unroll
        for (int g = 0; g < NG; ++g) {
            int ay = apix[g] >> wshift;
            int ax = apix[g] & (Wout - 1);
            int iy = ay * stride - pad + ky;
            int ix = ax * stride - pad + kx;
            av[g] = ((unsigned)iy < (unsigned)Hin) && ((unsigned)ix < (unsigned)Win);
            int ipix = av[g] ? iy * Win + ix : 0;
            abase[g] = (bbase + ipix) * CS + koff + klane;
        }
        const f16* wtap = Wt + (size_t)tap * OC * K;

#pragma unroll
        for (int k0 = 0; k0 < K; k0 += 32) {
            half8 a_h[NG], a_l[NG];
#pragma unroll
            for (int g = 0; g < NG; ++g) {
                a_h[g] = av[g] ? *(const half8*)(Ah + abase[g] + k0) : zero8;
                a_l[g] = av[g] ? *(const half8*)(Al + abase[g] + k0) : zero8;
            }
#pragma unroll
            for (int j = 0; j < 4; ++j) {
                half8 bv = *(const half8*)(wtap + woff[j] + k0);
#pragma unroll
                for (int g = 0; g < NG; ++g) {
                    acc[g][j]  = __builtin_amdgcn_mfma_f32_16x16x32_f16(a_h[g], bv, acc[g][j], 0, 0, 0);
                    acc2[g][j] = __builtin_amdgcn_mfma_f32_16x16x32_f16(a_l[g], bv, acc2[g][j], 0, 0, 0);
                }
            }
        }
    }

    const int Cc = (MODE == 0) ? (OC >> 1) : OC;
#pragma unroll
    for (int g = 0; g < NG; ++g) {
#pragma unroll
        for (int j = 0; j < 4; ++j) {
            const int oc = nb * 64 + j * 16 + (lane & 15);
            const float bv = bias[oc];
#pragma unroll
            for (int r = 0; r < 4; ++r) {
                const int pix = pixbase + 16 * g + ((lane >> 4) << 2) + r;
                const size_t pbase = (size_t)b * HWout + pix;
                float a = acc[g][j][r] + acc2[g][j][r] * (1.0f / 4096.0f) + bv;
                if (MODE == 0) {
                    float s = sigmoid_f(a);
                    if (oc < Cc) {
                        zout[pbase * Cc + oc] = s;
                    } else {
                        size_t hidx = pbase * CS + (oc - Cc);
                        float hv = (float)Ah[hidx] + (float)Al[hidx] * (1.0f / 4096.0f);
                        float rh = s * hv;
                        f16 hi, lo; splitf(rh, hi, lo);
                        size_t oidx = pbase * CS + Cc + oc;  // ch 2C + (oc-C)
                        Oh[oidx] = hi; Ol[oidx] = lo;
                    }
                } else if (MODE == 1) {
                    size_t hidx = pbase * CS + oc;
                    float hv = (float)Ah[hidx] + (float)Al[hidx] * (1.0f / 4096.0f);
                    float zv = zbuf[pbase * Cc + oc];
                    float hn = (1.f - zv) * hv + zv * tanhf(a);
                    f16 hi, lo; splitf(hn, hi, lo);
                    Oh[hidx] = hi; Ol[hidx] = lo;
                } else {
                    f16 hi, lo; splitf(a, hi, lo);
                    size_t oidx = pbase * OCS + okoff + oc;
                    Oh[oidx] = hi; Ol[oidx] = lo;
                }
            }
        }
    }
}

// ---------------------------------------------------------------------------
// conv1: IC=1, k4 s2 p1, 128x128 -> 64x64, OC=64.  Direct fp32, writes f16
// hi/lo into cat1 xt region (channels [64,128), CS=192).
// ---------------------------------------------------------------------------
__global__ __launch_bounds__(256) void conv1_k(
    const float* __restrict__ in, const float* __restrict__ w,
    const float* __restrict__ bias,
    f16* __restrict__ Oh, f16* __restrict__ Ol)
{
    const int b   = blockIdx.y;
    const int tid = threadIdx.x;
    const int px  = blockIdx.x * 64 + (tid & 63);
    const int ocg = tid >> 6;
    const int y = px >> 6, x = px & 63;
    const float* src = in + (size_t)b * 196608;
    float v[16];
#pragma unroll
    for (int ky = 0; ky < 4; ++ky)
#pragma unroll
        for (int kx = 0; kx < 4; ++kx) {
            int iy = 2 * y - 1 + ky, ix = 2 * x - 1 + kx;
            v[ky * 4 + kx] = ((unsigned)iy < 128u && (unsigned)ix < 128u) ? src[iy * 128 + ix] : 0.f;
        }
    size_t obase = ((size_t)b * 4096 + px) * 192 + 64 + ocg * 16;
#pragma unroll
    for (int o = 0; o < 16; ++o) {
        int oc = ocg * 16 + o;
        float s = bias[oc];
        const float* wr = w + oc * 16;
#pragma unroll
        for (int t = 0; t < 16; ++t) s += wr[t] * v[t];
        f16 hi, lo; splitf(s, hi, lo);
        Oh[obase + o] = hi; Ol[obase + o] = lo;
    }
}

// w[oc][ic][kh][kw] fp32 -> wt [tap][oc][ic'] f16 (RNE).
// perm=1: swap input-channel halves (zr convs: ref concat [x,h] -> cat [h,xt]).
__global__ __launch_bounds__(256) void prep_w(
    const float* __restrict__ w, f16* __restrict__ wt,
    int OC, int IC, int KK, int perm)
{
    int i = blockIdx.x * 256 + threadIdx.x;
    int total = OC * IC * KK;
    if (i >= total) return;
    int oc = i / (IC * KK);
    int r  = i - oc * (IC * KK);
    int ic = r / KK;
    int tap = r - ic * KK;
    int icn = perm ? ((ic < IC / 2) ? ic + IC / 2 : ic - IC / 2) : ic;
    wt[((size_t)tap * OC + oc) * IC + icn] = (f16)w[i];
}

// cat hi/lo h-region -> fp32 NCHW
__global__ __launch_bounds__(256) void cat_to_nchw(
    const f16* __restrict__ hi, const f16* __restrict__ lo,
    float* __restrict__ dst, int C, int HW, int CS)
{
    int i = blockIdx.x * 256 + threadIdx.x;
    int b = i / (C * HW);
    int r = i - b * (C * HW);
    int c = r / HW;
    int p = r - c * HW;
    size_t s = ((size_t)b * HW + p) * CS + c;
    dst[i] = (float)hi[s] + (float)lo[s] * (1.0f / 4096.0f);
}

// ---------------------------------------------------------------------------
extern "C" void kernel_launch(void* const* d_in, const int* in_sizes, int n_in,
                              void* d_out, int out_size, void* d_ws, size_t ws_size,
                              hipStream_t stream)
{
    (void)in_sizes; (void)n_in; (void)out_size; (void)ws_size;

    const float* input  = (const float*)d_in[0];
    const float* c1_w   = (const float*)d_in[1];
    const float* c1_b   = (const float*)d_in[2];
    const float* g1zr_w = (const float*)d_in[3];
    const float* g1zr_b = (const float*)d_in[4];
    const float* g1h_w  = (const float*)d_in[5];
    const float* g1h_b  = (const float*)d_in[6];
    const float* c2_w   = (const float*)d_in[7];
    const float* c2_b   = (const float*)d_in[8];
    const float* g2zr_w = (const float*)d_in[9];
    const float* g2zr_b = (const float*)d_in[10];
    const float* g2h_w  = (const float*)d_in[11];
    const float* g2h_b  = (const float*)d_in[12];
    const float* c3_w   = (const float*)d_in[13];
    const float* c3_b   = (const float*)d_in[14];
    const float* g3zr_w = (const float*)d_in[15];
    const float* g3zr_b = (const float*)d_in[16];
    const float* g3h_w  = (const float*)d_in[17];
    const float* g3h_b  = (const float*)d_in[18];

    float* out1 = (float*)d_out;                 // [8,64,64,64]  NCHW
    float* out2 = (float*)d_out + 2097152;       // [8,128,32,32]
    float* out3 = (float*)d_out + 3145728;       // [8,128,16,16]

    char* ws = (char*)d_ws;
    size_t off = 0;
    auto takeB = [&](size_t bytes) { char* p = ws + off; off += (bytes + 255) & ~(size_t)255; return p; };

    f16* wt_g1zr = (f16*)takeB(25 * 128 * 128 * 2);
    f16* wt_g1h  = (f16*)takeB(25 * 64 * 128 * 2);
    f16* wt_c2   = (f16*)takeB(16 * 128 * 64 * 2);
    f16* wt_g2zr = (f16*)takeB(25 * 256 * 256 * 2);
    f16* wt_g2h  = (f16*)takeB(25 * 128 * 256 * 2);
    f16* wt_c3   = (f16*)takeB(16 * 128 * 128 * 2);
    f16* wt_g3zr = (f16*)takeB(25 * 256 * 256 * 2);
    f16* wt_g3h  = (f16*)takeB(25 * 128 * 256 * 2);

    // stage cat buffers: layout [h | xt | rh], each C channels, f16 hi/lo
    const size_t cat1_n = (size_t)8 * 4096 * 192;  // C=64,  CS=192
    const size_t cat2_n = (size_t)8 * 1024 * 384;  // C=128, CS=384
    const size_t cat3_n = (size_t)8 * 256 * 384;   // C=128, CS=384
    f16* cat1h = (f16*)takeB(cat1_n * 2);
    f16* cat1l = (f16*)takeB(cat1_n * 2);
    f16* cat2h = (f16*)takeB(cat2_n * 2);
    f16* cat2l = (f16*)takeB(cat2_n * 2);
    f16* cat3h = (f16*)takeB(cat3_n * 2);
    f16* cat3l = (f16*)takeB(cat3_n * 2);
    float* z1 = (float*)takeB((size_t)8 * 4096 * 64 * 4);
    float* z2 = (float*)takeB((size_t)8 * 1024 * 128 * 4);
    float* z3 = (float*)takeB((size_t)8 * 256 * 128 * 4);

    hipMemsetAsync(cat1h, 0, cat1_n * 2, stream);
    hipMemsetAsync(cat1l, 0, cat1_n * 2, stream);
    hipMemsetAsync(cat2h, 0, cat2_n * 2, stream);
    hipMemsetAsync(cat2l, 0, cat2_n * 2, stream);
    hipMemsetAsync(cat3h, 0, cat3_n * 2, stream);
    hipMemsetAsync(cat3l, 0, cat3_n * 2, stream);

    auto prep = [&](const float* w, f16* wt, int OC, int IC, int KK, int perm) {
        int total = OC * IC * KK;
        prep_w<<<(total + 255) / 256, 256, 0, stream>>>(w, wt, OC, IC, KK, perm);
    };
    prep(g1zr_w, wt_g1zr, 128, 128, 25, 1);
    prep(g1h_w,  wt_g1h,  64, 128, 25, 0);
    prep(c2_w,   wt_c2,   128, 64, 16, 0);
    prep(g2zr_w, wt_g2zr, 256, 256, 25, 1);
    prep(g2h_w,  wt_g2h,  128, 256, 25, 0);
    prep(c3_w,   wt_c3,   128, 128, 16, 0);
    prep(g3zr_w, wt_g3zr, 256, 256, 25, 1);
    prep(g3h_w,  wt_g3h,  128, 256, 25, 0);

    for (int t = 0; t < 12; ++t) {
        // stage 1 @64x64, C=64, CS=192
        conv1_k<<<dim3(64, 8), 256, 0, stream>>>(
            input + (size_t)t * 16384, c1_w, c1_b, cat1h, cat1l);
        gemm_conv<5, 5, 128, 0, 2><<<dim3(32, 2, 8), 256, 0, stream>>>(
            cat1h, cat1l, 192, 0, wt_g1zr, g1zr_b,
            nullptr, z1, cat1h, cat1l, 0, 0,
            64, 64, 64, 6, 128, 1, 2);
        gemm_conv<5, 5, 128, 1, 1><<<dim3(64, 1, 8), 256, 0, stream>>>(
            cat1h, cat1l, 192, 64, wt_g1h, g1h_b,
            z1, nullptr, cat1h, cat1l, 0, 0,
            64, 64, 64, 6, 64, 1, 2);
        // c2: reads stage-1 h (ch[0,64)), writes stage-2 xt (ch[128,256))
        gemm_conv<4, 4, 64, 2, 1><<<dim3(16, 2, 8), 256, 0, stream>>>(
            cat1h, cat1l, 192, 0, wt_c2, c2_b,
            nullptr, nullptr, cat2h, cat2l, 384, 128,
            64, 64, 32, 5, 128, 2, 1);
        // stage 2 @32x32, C=128, CS=384
        gemm_conv<5, 5, 256, 0, 1><<<dim3(16, 4, 8), 256, 0, stream>>>(
            cat2h, cat2l, 384, 0, wt_g2zr, g2zr_b,
            nullptr, z2, cat2h, cat2l, 0, 0,
            32, 32, 32, 5, 256, 1, 2);
        gemm_conv<5, 5, 256, 1, 1><<<dim3(16, 2, 8), 256, 0, stream>>>(
            cat2h, cat2l, 384, 128, wt_g2h, g2h_b,
            z2, nullptr, cat2h, cat2l, 0, 0,
            32, 32, 32, 5, 128, 1, 2);
        // c3: reads stage-2 h, writes stage-3 xt
        gemm_conv<4, 4, 128, 2, 1><<<dim3(4, 2, 8), 256, 0, stream>>>(
            cat2h, cat2l, 384, 0, wt_c3, c3_b,
            nullptr, nullptr, cat3h, cat3l, 384, 128,
            32, 32, 16, 4, 128, 2, 1);
        // stage 3 @16x16, C=128, CS=384
        gemm_conv<5, 5, 256, 0, 1><<<dim3(4, 4, 8), 256, 0, stream>>>(
            cat3h, cat3l, 384, 0, wt_g3zr, g3zr_b,
            nullptr, z3, cat3h, cat3l, 0, 0,
            16, 16, 16, 4, 256, 1, 2);
        gemm_conv<5, 5, 256, 1, 1><<<dim3(4, 2, 8), 256, 0, stream>>>(
            cat3h, cat3l, 384, 128, wt_g3h, g3h_b,
            z3, nullptr, cat3h, cat3l, 0, 0,
            16, 16, 16, 4, 128, 1, 2);
    }

    cat_to_nchw<<<8192, 256, 0, stream>>>(cat1h, cat1l, out1, 64, 4096, 192);
    cat_to_nchw<<<4096, 256, 0, stream>>>(cat2h, cat2l, out2, 128, 1024, 384);
    cat_to_nchw<<<1024, 256, 0, stream>>>(cat3h, cat3l, out3, 128, 256, 384);
}

// Round 6
// 12935.493 us; speedup vs baseline: 5.6781x; 1.1596x over previous
//
#include <hip/hip_runtime.h>
#include <math.h>

typedef _Float16 f16;
typedef __attribute__((ext_vector_type(8))) _Float16 half8;
typedef __attribute__((ext_vector_type(4))) float f32x4;

static __device__ __forceinline__ float sigmoid_f(float x) { return 1.0f / (1.0f + expf(-x)); }

// exact split: x == (float)hi + (float)lo / 4096 (lo pre-scaled to dodge denormals)
static __device__ __forceinline__ void splitf(float x, f16& hi, f16& lo) {
    hi = (f16)x;
    float r = x - (float)hi;
    lo = (f16)(r * 4096.0f);
}

// ---------------------------------------------------------------------------
// Tap-decomposed implicit-GEMM conv, f16 MFMA, 2-term activation split,
// fp32 accumulate, NO LDS, NO barriers, NO boundary branches (spatial halo=2,
// zero-filled).  Manual register software-pipeline of depth D over the flat
// (tap x k-chunk) step sequence; per-tap address advance is a wave-uniform
// pointer bump.  Activations f16 hi/lo planes, padded NHWC (CS channel
// stride, KOFF window offset into the per-stage cat layout [h | xt | rh]).
// Weights f16 [tap][oc][ic].  Wave owns NG*16 px x NOC*16 oc.
// A-frag: lane&15=pixel, k=(lane>>4)*8+j ; B-frag: lane&15=oc, same k.
// D-frag: col(oc)=lane&15, row(pixel)=(lane>>4)*4+reg  [HW-verified layouts]
// MODE 0: zr -> z=sigmoid fp32 (oc<C); rh=sigmoid*h -> cat ch[2C..3C)
// MODE 1: h~ -> h' = (1-z)*h + z*tanh  -> cat ch[0..C)
// MODE 2: conv+bias -> next-stage cat xt region
// ---------------------------------------------------------------------------
template <int KH, int KW, int K, int MODE, int NG, int NOC, int D,
          int CS, int KOFF, int HIN, int WIN, int HOUT, int WOUT,
          int OC, int STRIDE, int PAD, int OCS, int OKOFF>
__global__ __launch_bounds__(256) void gemm_conv(
    const f16* Ah, const f16* Al,
    const f16* __restrict__ Wt, const float* __restrict__ bias,
    const float* __restrict__ zbuf, float* __restrict__ zout,
    f16* Oh, f16* Ol)
{
    constexpr int WP   = WIN + 4;
    constexpr int HPW  = (HIN + 4) * WP;
    constexpr int OWP  = WOUT + 4;
    constexpr int OHPW = (HOUT + 4) * OWP;
    constexpr int WSH  = (WOUT == 64) ? 6 : ((WOUT == 32) ? 5 : 4);
    constexpr int KPT  = K / 32;
    constexpr int NSTEP = KH * KW * KPT;
    static_assert(NSTEP % D == 0, "NSTEP divisible by D");

    const int b    = blockIdx.z;
    const int lane = threadIdx.x & 63;
    const int wave = threadIdx.x >> 6;
    const int pixbase = (blockIdx.x * 4 + wave) * (NG * 16);
    const int klane = (lane >> 4) * 8;
    const int ocl   = lane & 15;
    const int ocb   = blockIdx.y * (NOC * 16);

    // load iterators (per-lane pointers; tap advance is wave-uniform delta)
    const f16* ph[NG];
    const f16* pl[NG];
#pragma unroll
    for (int g = 0; g < NG; ++g) {
        int apix = pixbase + 16 * g + ocl;
        int y = apix >> WSH, x = apix & (WOUT - 1);
        size_t o = ((size_t)b * HPW + (size_t)(y * STRIDE - PAD + 2) * WP +
                    (x * STRIDE - PAD + 2)) * CS + KOFF + klane;
        ph[g] = Ah + o;
        pl[g] = Al + o;
    }
    const f16* pw = Wt + (size_t)(ocb + ocl) * K + klane;

    int lk = 0, lkx = 0;
    auto advance = [&]() {
#pragma unroll
        for (int g = 0; g < NG; ++g) { ph[g] += 32; pl[g] += 32; }
        pw += 32;
        if (++lk == KPT) {
            lk = 0;
            int pixstep = 1;
            if (++lkx == KW) { lkx = 0; pixstep = WP - (KW - 1); }
            const long ad = (long)pixstep * CS - K;
#pragma unroll
            for (int g = 0; g < NG; ++g) { ph[g] += ad; pl[g] += ad; }
            pw += (long)(OC - 1) * K;
        }
    };

    half8 bh[D][NG], bl[D][NG], bw[D][NOC];
    f32x4 acc[NG][NOC] = {};
    f32x4 acc2[NG][NOC] = {};

    // prologue: load steps 0..D-2
#pragma unroll
    for (int s = 0; s < D - 1; ++s) {
#pragma unroll
        for (int g = 0; g < NG; ++g) {
            bh[s][g] = *(const half8*)ph[g];
            bl[s][g] = *(const half8*)pl[g];
        }
#pragma unroll
        for (int j = 0; j < NOC; ++j)
            bw[s][j] = *(const half8*)(pw + (size_t)j * 16 * K);
        advance();
    }

#pragma unroll 1
    for (int ii = 0; ii < NSTEP / D; ++ii) {
#pragma unroll
        for (int d = 0; d < D; ++d) {
            const int ls = (d + D - 1) % D;  // slot for step s+D-1
#pragma unroll
            for (int g = 0; g < NG; ++g) {
                bh[ls][g] = *(const half8*)ph[g];
                bl[ls][g] = *(const half8*)pl[g];
            }
#pragma unroll
            for (int j = 0; j < NOC; ++j)
                bw[ls][j] = *(const half8*)(pw + (size_t)j * 16 * K);
            advance();
#pragma unroll
            for (int j = 0; j < NOC; ++j)
#pragma unroll
                for (int g = 0; g < NG; ++g) {
                    acc[g][j]  = __builtin_amdgcn_mfma_f32_16x16x32_f16(bh[d][g], bw[d][j], acc[g][j], 0, 0, 0);
                    acc2[g][j] = __builtin_amdgcn_mfma_f32_16x16x32_f16(bl[d][g], bw[d][j], acc2[g][j], 0, 0, 0);
                }
        }
    }

    constexpr int Cc = (MODE == 0) ? (OC >> 1) : OC;
#pragma unroll
    for (int g = 0; g < NG; ++g) {
#pragma unroll
        for (int j = 0; j < NOC; ++j) {
            const int oc = ocb + j * 16 + ocl;
            const float bv = bias[oc];
#pragma unroll
            for (int r = 0; r < 4; ++r) {
                const int pix = pixbase + 16 * g + ((lane >> 4) << 2) + r;
                const int y = pix >> WSH, x = pix & (WOUT - 1);
                const size_t pp = (size_t)b * OHPW + (size_t)(y + 2) * OWP + (x + 2);
                const size_t pz = (size_t)b * (HOUT * WOUT) + pix;
                float a = acc[g][j][r] + acc2[g][j][r] * (1.0f / 4096.0f) + bv;
                if (MODE == 0) {
                    float s = sigmoid_f(a);
                    if (oc < Cc) {
                        zout[pz * Cc + oc] = s;
                    } else {
                        size_t hidx = pp * OCS + (oc - Cc);
                        float hv = (float)Ah[hidx] + (float)Al[hidx] * (1.0f / 4096.0f);
                        float rh = s * hv;
                        f16 hi, lo; splitf(rh, hi, lo);
                        size_t oi = pp * OCS + Cc + oc;  // channel 2C + (oc-C)
                        Oh[oi] = hi; Ol[oi] = lo;
                    }
                } else if (MODE == 1) {
                    size_t hidx = pp * OCS + oc;
                    float hv = (float)Ah[hidx] + (float)Al[hidx] * (1.0f / 4096.0f);
                    float zv = zbuf[pz * Cc + oc];
                    float hn = (1.f - zv) * hv + zv * tanhf(a);
                    f16 hi, lo; splitf(hn, hi, lo);
                    Oh[hidx] = hi; Ol[hidx] = lo;
                } else {
                    f16 hi, lo; splitf(a, hi, lo);
                    size_t oi = pp * OCS + OKOFF + oc;
                    Oh[oi] = hi; Ol[oi] = lo;
                }
            }
        }
    }
}

// ---------------------------------------------------------------------------
// conv1: IC=1, k4 s2 p1, 128x128 -> 64x64, OC=64.  Direct fp32; writes f16
// hi/lo into padded cat1 xt region (channels [64,128), CS=192, halo 2).
// ---------------------------------------------------------------------------
__global__ __launch_bounds__(256) void conv1_k(
    const float* __restrict__ in, const float* __restrict__ w,
    const float* __restrict__ bias, f16* Oh, f16* Ol)
{
    const int b   = blockIdx.y;
    const int tid = threadIdx.x;
    const int px  = blockIdx.x * 64 + (tid & 63);
    const int ocg = tid >> 6;
    const int y = px >> 6, x = px & 63;
    const float* src = in + (size_t)b * 196608;
    float v[16];
#pragma unroll
    for (int ky = 0; ky < 4; ++ky)
#pragma unroll
        for (int kx = 0; kx < 4; ++kx) {
            int iy = 2 * y - 1 + ky, ix = 2 * x - 1 + kx;
            v[ky * 4 + kx] = ((unsigned)iy < 128u && (unsigned)ix < 128u) ? src[iy * 128 + ix] : 0.f;
        }
    size_t obase = ((size_t)b * 4624 + (size_t)(y + 2) * 68 + (x + 2)) * 192 + 64 + ocg * 16;
#pragma unroll
    for (int o = 0; o < 16; ++o) {
        int oc = ocg * 16 + o;
        float s = bias[oc];
        const float* wr = w + oc * 16;
#pragma unroll
        for (int t = 0; t < 16; ++t) s += wr[t] * v[t];
        f16 hi, lo; splitf(s, hi, lo);
        Oh[obase + o] = hi; Ol[obase + o] = lo;
    }
}

// w[oc][ic][kh][kw] fp32 -> wt [tap][oc][ic'] f16 (RNE).
// perm=1: swap input-channel halves (zr convs: ref concat [x,h] -> cat [h,xt]).
__global__ __launch_bounds__(256) void prep_w(
    const float* __restrict__ w, f16* __restrict__ wt,
    int OC, int IC, int KK, int perm)
{
    int i = blockIdx.x * 256 + threadIdx.x;
    int total = OC * IC * KK;
    if (i >= total) return;
    int oc = i / (IC * KK);
    int r  = i - oc * (IC * KK);
    int ic = r / KK;
    int tap = r - ic * KK;
    int icn = perm ? ((ic < IC / 2) ? ic + IC / 2 : ic - IC / 2) : ic;
    wt[((size_t)tap * OC + oc) * IC + icn] = (f16)w[i];
}

// padded cat hi/lo h-region -> fp32 NCHW
__global__ __launch_bounds__(256) void cat_to_nchw(
    const f16* __restrict__ hi, const f16* __restrict__ lo,
    float* __restrict__ dst, int C, int HW, int wsh, int WP, int HPW, int CS)
{
    int i = blockIdx.x * 256 + threadIdx.x;
    int b = i / (C * HW);
    int r = i - b * (C * HW);
    int c = r / HW;
    int p = r - c * HW;
    int y = p >> wsh, x = p & ((1 << wsh) - 1);
    size_t s = ((size_t)b * HPW + (size_t)(y + 2) * WP + (x + 2)) * CS + c;
    dst[i] = (float)hi[s] + (float)lo[s] * (1.0f / 4096.0f);
}

// ---------------------------------------------------------------------------
extern "C" void kernel_launch(void* const* d_in, const int* in_sizes, int n_in,
                              void* d_out, int out_size, void* d_ws, size_t ws_size,
                              hipStream_t stream)
{
    (void)in_sizes; (void)n_in; (void)out_size; (void)ws_size;

    const float* input  = (const float*)d_in[0];
    const float* c1_w   = (const float*)d_in[1];
    const float* c1_b   = (const float*)d_in[2];
    const float* g1zr_w = (const float*)d_in[3];
    const float* g1zr_b = (const float*)d_in[4];
    const float* g1h_w  = (const float*)d_in[5];
    const float* g1h_b  = (const float*)d_in[6];
    const float* c2_w   = (const float*)d_in[7];
    const float* c2_b   = (const float*)d_in[8];
    const float* g2zr_w = (const float*)d_in[9];
    const float* g2zr_b = (const float*)d_in[10];
    const float* g2h_w  = (const float*)d_in[11];
    const float* g2h_b  = (const float*)d_in[12];
    const float* c3_w   = (const float*)d_in[13];
    const float* c3_b   = (const float*)d_in[14];
    const float* g3zr_w = (const float*)d_in[15];
    const float* g3zr_b = (const float*)d_in[16];
    const float* g3h_w  = (const float*)d_in[17];
    const float* g3h_b  = (const float*)d_in[18];

    float* out1 = (float*)d_out;                 // [8,64,64,64]  NCHW
    float* out2 = (float*)d_out + 2097152;       // [8,128,32,32]
    float* out3 = (float*)d_out + 3145728;       // [8,128,16,16]

    char* ws = (char*)d_ws;
    size_t off = 0;
    auto takeB = [&](size_t bytes) { char* p = ws + off; off += (bytes + 255) & ~(size_t)255; return p; };

    // weights (+slack for pipeline overrun reads)
    const size_t WSLACK = 300000;
    f16* wt_g1zr = (f16*)takeB((size_t)25 * 128 * 128 * 2 + WSLACK);
    f16* wt_g1h  = (f16*)takeB((size_t)25 * 64 * 128 * 2 + WSLACK);
    f16* wt_c2   = (f16*)takeB((size_t)16 * 128 * 64 * 2 + WSLACK);
    f16* wt_g2zr = (f16*)takeB((size_t)25 * 256 * 256 * 2 + WSLACK);
    f16* wt_g2h  = (f16*)takeB((size_t)25 * 128 * 256 * 2 + WSLACK);
    f16* wt_c3   = (f16*)takeB((size_t)16 * 128 * 128 * 2 + WSLACK);
    f16* wt_g3zr = (f16*)takeB((size_t)25 * 256 * 256 * 2 + WSLACK);
    f16* wt_g3h  = (f16*)takeB((size_t)25 * 128 * 256 * 2 + WSLACK);

    // padded cat buffers (halo=2): [h | xt | rh] per pixel, f16 hi/lo planes
    const size_t cat1_n = (size_t)8 * 4624 * 192;  // 68x68, CS=192
    const size_t cat2_n = (size_t)8 * 1296 * 384;  // 36x36, CS=384
    const size_t cat3_n = (size_t)8 * 400 * 384;   // 20x20, CS=384
    const size_t ASLACK = 65536;
    f16* cat1h = (f16*)takeB(cat1_n * 2 + ASLACK);
    f16* cat1l = (f16*)takeB(cat1_n * 2 + ASLACK);
    f16* cat2h = (f16*)takeB(cat2_n * 2 + ASLACK);
    f16* cat2l = (f16*)takeB(cat2_n * 2 + ASLACK);
    f16* cat3h = (f16*)takeB(cat3_n * 2 + ASLACK);
    f16* cat3l = (f16*)takeB(cat3_n * 2 + ASLACK);
    float* z1 = (float*)takeB((size_t)8 * 4096 * 64 * 4);
    float* z2 = (float*)takeB((size_t)8 * 1024 * 128 * 4);
    float* z3 = (float*)takeB((size_t)8 * 256 * 128 * 4);

    hipMemsetAsync(cat1h, 0, cat1_n * 2, stream);
    hipMemsetAsync(cat1l, 0, cat1_n * 2, stream);
    hipMemsetAsync(cat2h, 0, cat2_n * 2, stream);
    hipMemsetAsync(cat2l, 0, cat2_n * 2, stream);
    hipMemsetAsync(cat3h, 0, cat3_n * 2, stream);
    hipMemsetAsync(cat3l, 0, cat3_n * 2, stream);

    auto prep = [&](const float* w, f16* wt, int OC, int IC, int KK, int perm) {
        int total = OC * IC * KK;
        prep_w<<<(total + 255) / 256, 256, 0, stream>>>(w, wt, OC, IC, KK, perm);
    };
    prep(g1zr_w, wt_g1zr, 128, 128, 25, 1);
    prep(g1h_w,  wt_g1h,  64, 128, 25, 0);
    prep(c2_w,   wt_c2,   128, 64, 16, 0);
    prep(g2zr_w, wt_g2zr, 256, 256, 25, 1);
    prep(g2h_w,  wt_g2h,  128, 256, 25, 0);
    prep(c3_w,   wt_c3,   128, 128, 16, 0);
    prep(g3zr_w, wt_g3zr, 256, 256, 25, 1);
    prep(g3h_w,  wt_g3h,  128, 256, 25, 0);

    for (int t = 0; t < 12; ++t) {
        // stage 1 @64x64, C=64, CS=192
        conv1_k<<<dim3(64, 8), 256, 0, stream>>>(
            input + (size_t)t * 16384, c1_w, c1_b, cat1h, cat1l);
        gemm_conv<5, 5, 128, 0, 2, 4, 2, 192, 0, 64, 64, 64, 64, 128, 1, 2, 192, 0>
            <<<dim3(32, 2, 8), 256, 0, stream>>>(
            cat1h, cat1l, wt_g1zr, g1zr_b, nullptr, z1, cat1h, cat1l);
        gemm_conv<5, 5, 128, 1, 1, 4, 4, 192, 64, 64, 64, 64, 64, 64, 1, 2, 192, 0>
            <<<dim3(64, 1, 8), 256, 0, stream>>>(
            cat1h, cat1l, wt_g1h, g1h_b, z1, nullptr, cat1h, cat1l);
        // c2: reads stage-1 h (ch[0,64)), writes stage-2 xt (ch[128,256))
        gemm_conv<4, 4, 64, 2, 1, 2, 4, 192, 0, 64, 64, 32, 32, 128, 2, 1, 384, 128>
            <<<dim3(16, 4, 8), 256, 0, stream>>>(
            cat1h, cat1l, wt_c2, c2_b, nullptr, nullptr, cat2h, cat2l);
        // stage 2 @32x32, C=128, CS=384
        gemm_conv<5, 5, 256, 0, 1, 4, 4, 384, 0, 32, 32, 32, 32, 256, 1, 2, 384, 0>
            <<<dim3(16, 4, 8), 256, 0, stream>>>(
            cat2h, cat2l, wt_g2zr, g2zr_b, nullptr, z2, cat2h, cat2l);
        gemm_conv<5, 5, 256, 1, 1, 2, 4, 384, 128, 32, 32, 32, 32, 128, 1, 2, 384, 0>
            <<<dim3(16, 4, 8), 256, 0, stream>>>(
            cat2h, cat2l, wt_g2h, g2h_b, z2, nullptr, cat2h, cat2l);
        // c3: reads stage-2 h, writes stage-3 xt
        gemm_conv<4, 4, 128, 2, 1, 1, 4, 384, 0, 32, 32, 16, 16, 128, 2, 1, 384, 128>
            <<<dim3(4, 8, 8), 256, 0, stream>>>(
            cat2h, cat2l, wt_c3, c3_b, nullptr, nullptr, cat3h, cat3l);
        // stage 3 @16x16, C=128, CS=384
        gemm_conv<5, 5, 256, 0, 1, 1, 4, 384, 0, 16, 16, 16, 16, 256, 1, 2, 384, 0>
            <<<dim3(4, 16, 8), 256, 0, stream>>>(
            cat3h, cat3l, wt_g3zr, g3zr_b, nullptr, z3, cat3h, cat3l);
        gemm_conv<5, 5, 256, 1, 1, 1, 4, 384, 128, 16, 16, 16, 16, 128, 1, 2, 384, 0>
            <<<dim3(4, 8, 8), 256, 0, stream>>>(
            cat3h, cat3l, wt_g3h, g3h_b, z3, nullptr, cat3h, cat3l);
    }

    cat_to_nchw<<<8192, 256, 0, stream>>>(cat1h, cat1l, out1, 64, 4096, 6, 68, 4624, 192);
    cat_to_nchw<<<4096, 256, 0, stream>>>(cat2h, cat2l, out2, 128, 1024, 5, 36, 1296, 384);
    cat_to_nchw<<<1024, 256, 0, stream>>>(cat3h, cat3l, out3, 128, 256, 4, 20, 400, 384);
}